// Round 1
// baseline (358.236 us; speedup 1.0000x reference)
//
#include <hip/hip_runtime.h>
#include <math.h>

#define N_NODES 50000
#define N_EDGES 400000
#define R_REL   35
#define B_BASES 12
#define C_DIM   128
#define T_TYPES 4
#define HL_DIM  38
#define OUT_DIM 2

// workspace layout (float offsets)
#define OFF_W    0        // w[R][2][C] = 8960 floats
#define OFF_WQ   8960     // wq[R][2]   = 70
#define OFF_WK   9040     // wk[R][2]   = 70
#define OFF_LE   9120     // le[2]
#define OFF_DEN  9216     // den[N] = 50000   (16B aligned: 9216*4 % 16 == 0)
#define OFF_S    59216    // s[N][R][2] = 3,500,000
#define ZERO_FLOATS (N_NODES + N_NODES*R_REL*2)   // den + s contiguous = 3,550,000

// ---------------- zero init (avoid hipMemsetAsync, keep capture trivially safe)
__global__ void zero_kernel(float4* __restrict__ p, int n4) {
    int i = blockIdx.x * blockDim.x + threadIdx.x;
    if (i < n4) p[i] = make_float4(0.f, 0.f, 0.f, 0.f);
}

// ---------------- tiny precompute: w = att_rel@basis, wq/wk = w@{q,k}, le = lin_edge_W@e_att
__global__ void precompute_kernel(const float* __restrict__ basis,    // [B,2,C]
                                  const float* __restrict__ att_rel,  // [R,B]
                                  const float* __restrict__ q_att,    // [C]
                                  const float* __restrict__ k_att,    // [C]
                                  const float* __restrict__ e_att,    // [C]
                                  const float* __restrict__ lin_edge_W, // [2,C]
                                  float* __restrict__ ws) {
    float* w  = ws + OFF_W;
    float* wq = ws + OFF_WQ;
    float* wk = ws + OFF_WK;
    float* le = ws + OFF_LE;
    int tid = threadIdx.x;
    for (int idx = tid; idx < R_REL * 2 * C_DIM; idx += blockDim.x) {
        int c  = idx & (C_DIM - 1);
        int ri = idx >> 7;          // r*2+i
        int i  = ri & 1;
        int r  = ri >> 1;
        float acc = 0.f;
        #pragma unroll
        for (int b = 0; b < B_BASES; ++b)
            acc += att_rel[r * B_BASES + b] * basis[(b * 2 + i) * C_DIM + c];
        w[idx] = acc;
    }
    __syncthreads();   // block-level fence: w visible to same-block readers
    for (int idx = tid; idx < R_REL * 2; idx += blockDim.x) {
        float aq = 0.f, ak = 0.f;
        for (int c = 0; c < C_DIM; ++c) {
            float wv = w[idx * C_DIM + c];
            aq += wv * q_att[c];
            ak += wv * k_att[c];
        }
        wq[idx] = aq;
        wk[idx] = ak;
    }
    if (tid < 2) {
        float acc = 0.f;
        for (int c = 0; c < C_DIM; ++c)
            acc += lin_edge_W[tid * C_DIM + c] * e_att[c];
        le[tid] = acc;
    }
}

// ---------------- edge pass: alpha -> exp -> 3 atomics (den, s[dst,r,0], s[dst,r,1])
__global__ __launch_bounds__(256) void edge_kernel(
        const float* __restrict__ x,           // [N,2]
        const int*   __restrict__ edge_index,  // [2,E]
        const int*   __restrict__ edge_type,   // [E]
        const float* __restrict__ edge_attr,   // [E,2]
        const float* __restrict__ ws_ro,
        float* __restrict__ den,
        float* __restrict__ s) {
    __shared__ float s_wq[R_REL * 2];
    __shared__ float s_wk[R_REL * 2];
    __shared__ float s_le[2];
    int tid = threadIdx.x;
    if (tid < R_REL * 2) {
        s_wq[tid] = ws_ro[OFF_WQ + tid];
        s_wk[tid] = ws_ro[OFF_WK + tid];
    }
    if (tid < 2) s_le[tid] = ws_ro[OFF_LE + tid];
    __syncthreads();

    int e = blockIdx.x * blockDim.x + tid;
    if (e >= N_EDGES) return;
    int src = edge_index[e];
    int dst = edge_index[N_EDGES + e];
    int r   = edge_type[e];
    float2 ea = *(const float2*)(edge_attr + 2 * e);
    float2 xs = *(const float2*)(x + 2 * src);
    float2 xd = *(const float2*)(x + 2 * dst);
    float alpha = xd.x * s_wq[2 * r] + xd.y * s_wq[2 * r + 1]
                + xs.x * s_wk[2 * r] + xs.y * s_wk[2 * r + 1]
                + ea.x * s_le[0]     + ea.y * s_le[1];
    alpha = alpha > 0.f ? alpha : 0.2f * alpha;   // leaky_relu 0.2
    float ex = expf(alpha);                       // alpha bounded (~|2|): no max-shift needed
    atomicAdd(&den[dst], ex);
    atomicAdd(&s[dst * (R_REL * 2) + 2 * r],     ex * xs.x);
    atomicAdd(&s[dst * (R_REL * 2) + 2 * r + 1], ex * xs.y);
}

// ---------------- node pass: agg recombine + bias + activation + 4-layer per-type MLP
// one wave per node; 4 nodes per 256-thread block
__global__ __launch_bounds__(256) void node_kernel(
        const int*   __restrict__ node_type,
        const float* __restrict__ ws,
        const float* __restrict__ conv_bias,  // [C]
        const float* __restrict__ lin0_W, const float* __restrict__ lin0_b,
        const float* __restrict__ lin1_W, const float* __restrict__ lin1_b,
        const float* __restrict__ lin2_W, const float* __restrict__ lin2_b,
        const float* __restrict__ fin_W,  const float* __restrict__ fin_b,
        float* __restrict__ out) {
    const float* w   = ws + OFF_W;
    const float* den = ws + OFF_DEN;
    const float* s   = ws + OFF_S;

    __shared__ float lds_h[4][C_DIM];
    __shared__ float lds_yA[4][HL_DIM];
    __shared__ float lds_yB[4][HL_DIM];

    int tid  = threadIdx.x;
    int wv   = tid >> 6;
    int lane = tid & 63;
    int n = blockIdx.x * 4 + wv;   // 50000 = 12500*4, always valid

    float dn = den[n] + 1e-16f;
    int   t  = node_type[n];

    // --- agg[c] = (sum_{r,i} s[n,r,i] * w[r,i,c]) / dn ; lane covers c=lane, c=lane+64
    float acc0 = 0.f, acc1 = 0.f;
    const float* sn = s + n * (R_REL * 2);
    for (int ri = 0; ri < R_REL * 2; ri += 2) {
        float2 sv = *(const float2*)(sn + ri);      // wave-uniform values
        if (sv.x != 0.f) {                          // wave-uniform branch (cheap skip)
            acc0 += sv.x * w[ri * C_DIM + lane];
            acc1 += sv.x * w[ri * C_DIM + 64 + lane];
        }
        if (sv.y != 0.f) {
            acc0 += sv.y * w[(ri + 1) * C_DIM + lane];
            acc1 += sv.y * w[(ri + 1) * C_DIM + 64 + lane];
        }
    }
    float h0 = acc0 / dn + conv_bias[lane];
    float h1 = acc1 / dn + conv_bias[64 + lane];
    // relu(leaky_relu(x,0.2)) == relu(x)
    lds_h[wv][lane]      = h0 > 0.f ? h0 : 0.f;
    lds_h[wv][64 + lane] = h1 > 0.f ? h1 : 0.f;
    __syncthreads();

    // --- lin0: [128] -> [38]
    const float* W0 = lin0_W + t * C_DIM * HL_DIM;
    if (lane < HL_DIM) {
        float y = 0.f;
        #pragma unroll 8
        for (int c = 0; c < C_DIM; ++c)
            y += lds_h[wv][c] * W0[c * HL_DIM + lane];
        y += lin0_b[t * HL_DIM + lane];
        lds_yA[wv][lane] = y > 0.f ? y : 0.f;       // relu feeds lin1
    }
    __syncthreads();

    // --- lin1: [38] -> [38]
    const float* W1 = lin1_W + t * HL_DIM * HL_DIM;
    if (lane < HL_DIM) {
        float y = 0.f;
        #pragma unroll
        for (int k = 0; k < HL_DIM; ++k)
            y += lds_yA[wv][k] * W1[k * HL_DIM + lane];
        y += lin1_b[t * HL_DIM + lane];
        lds_yB[wv][lane] = y > 0.f ? y : 0.f;       // relu feeds lin2
    }
    __syncthreads();

    // --- lin2: [38] -> [38] (NO relu on output; fin consumes raw)
    const float* W2 = lin2_W + t * HL_DIM * HL_DIM;
    if (lane < HL_DIM) {
        float y = 0.f;
        #pragma unroll
        for (int k = 0; k < HL_DIM; ++k)
            y += lds_yB[wv][k] * W2[k * HL_DIM + lane];
        y += lin2_b[t * HL_DIM + lane];
        lds_yA[wv][lane] = y;
    }
    __syncthreads();

    // --- fin: [38] -> [2], type-0 abs on second output
    if (lane < OUT_DIM) {
        const float* FW = fin_W + t * HL_DIM * OUT_DIM;
        float o = 0.f;
        #pragma unroll
        for (int k = 0; k < HL_DIM; ++k)
            o += lds_yA[wv][k] * FW[k * OUT_DIM + lane];
        o += fin_b[t * OUT_DIM + lane];
        if (t == 0 && lane == 1) o = fabsf(o);
        out[n * 2 + lane] = o;
    }
}

extern "C" void kernel_launch(void* const* d_in, const int* in_sizes, int n_in,
                              void* d_out, int out_size, void* d_ws, size_t ws_size,
                              hipStream_t stream) {
    const float* x          = (const float*)d_in[0];
    const int*   edge_index = (const int*)  d_in[1];
    const int*   edge_type  = (const int*)  d_in[2];
    const float* edge_attr  = (const float*)d_in[3];
    const int*   node_type  = (const int*)  d_in[4];
    const float* basis      = (const float*)d_in[5];
    const float* att_rel    = (const float*)d_in[6];
    const float* q_att      = (const float*)d_in[7];
    const float* k_att      = (const float*)d_in[8];
    const float* e_att      = (const float*)d_in[9];
    const float* lin_edge_W = (const float*)d_in[10];
    const float* conv_bias  = (const float*)d_in[11];
    const float* lin0_W     = (const float*)d_in[12];
    const float* lin0_b     = (const float*)d_in[13];
    const float* lin1_W     = (const float*)d_in[14];
    const float* lin1_b     = (const float*)d_in[15];
    const float* lin2_W     = (const float*)d_in[16];
    const float* lin2_b     = (const float*)d_in[17];
    const float* fin_W      = (const float*)d_in[18];
    const float* fin_b      = (const float*)d_in[19];

    float* ws  = (float*)d_ws;
    float* out = (float*)d_out;

    // zero den+s (contiguous, 16B-aligned, count divisible by 4)
    int n4 = ZERO_FLOATS / 4;   // 887,500 float4s
    zero_kernel<<<(n4 + 255) / 256, 256, 0, stream>>>((float4*)(ws + OFF_DEN), n4);

    precompute_kernel<<<1, 256, 0, stream>>>(basis, att_rel, q_att, k_att, e_att,
                                             lin_edge_W, ws);

    edge_kernel<<<(N_EDGES + 255) / 256, 256, 0, stream>>>(
        x, edge_index, edge_type, edge_attr, ws, ws + OFF_DEN, ws + OFF_S);

    node_kernel<<<N_NODES / 4, 256, 0, stream>>>(
        node_type, ws, conv_bias,
        lin0_W, lin0_b, lin1_W, lin1_b, lin2_W, lin2_b, fin_W, fin_b, out);
}